// Round 9
// baseline (158.865 us; speedup 1.0000x reference)
//
#include <hip/hip_runtime.h>
#include <hip/hip_bf16.h>
#include <math.h>

// Problem constants
#define B_   512
#define KEV  64
#define NN   1024
#define DD   128
#define EE_  1024
#define HH   256
#define PP   12
#define BK   128                 // event K-step (elements of EE)
#define NSTEP (EE_ / BK)         // 8

typedef __bf16 bf16x8 __attribute__((ext_vector_type(8)));
typedef float  f32x4  __attribute__((ext_vector_type(4)));
typedef unsigned short ushort8_t __attribute__((ext_vector_type(8)));

static __device__ __forceinline__ unsigned short f2bf(float f) {
    unsigned int u = __builtin_bit_cast(unsigned int, f);
    u = (u + 0x7FFFu + ((u >> 16) & 1u)) >> 16;   // RNE
    return (unsigned short)u;
}

// ---------------------------------------------------------------------------
// prep (blocks 0..255): W_t f32 -> bf16.  block 256: detect dtypes + build Wc.
//   flags[0] = event_idx is int64 (1) or int32 (0)
//   flags[1] = event_mask repr: 0=uint8, 1=int32, 2=int64
// ---------------------------------------------------------------------------
__global__ __launch_bounds__(256) void prep_kernel(
    const float* __restrict__ Wt,
    const float* __restrict__ Wmm,
    const float* __restrict__ Wts,
    const unsigned int* __restrict__ idxW,
    const unsigned int* __restrict__ mskW,
    unsigned short* __restrict__ WtBf,
    float* __restrict__ Wc,
    int* __restrict__ flags)
{
    if (blockIdx.x < 256) {
        int i4 = (blockIdx.x * 256 + threadIdx.x) * 4;
        const float4 v = *reinterpret_cast<const float4*>(Wt + i4);
        ushort4 o = make_ushort4(f2bf(v.x), f2bf(v.y), f2bf(v.z), f2bf(v.w));
        *reinterpret_cast<ushort4*>(WtBf + i4) = o;
        return;
    }
    // block 256: detect + Wc
    __shared__ int any_nz;
    if (threadIdx.x == 0) any_nz = 0;
    __syncthreads();
    int local = 0;
    for (int k = threadIdx.x; k < (B_ * KEV) / 2; k += 256)
        local |= (idxW[2 * k + 1] != 0u);
    if (local) atomicOr(&any_nz, 1);
    for (int k = threadIdx.x; k < PP * DD; k += 256) {
        int p = k >> 7, d = k & 127;
        Wc[k] = Wmm[p * (HH + DD) + HH + d] + Wts[p * DD + d];
    }
    __syncthreads();
    if (threadIdx.x == 0) {
        flags[0] = any_nz ? 0 : 1;                 // 1 => idx is int64
        unsigned int w0 = mskW[0], w1 = mskW[1];
        flags[1] = (w0 == 0x01010101u) ? 0 : ((w1 == 0u) ? 2 : 1);
    }
}

// ---------------------------------------------------------------------------
// event path (proven R4 pipeline): per-batch GEMM [64x1024]x[1024x256] bf16
// MFMA, BK=128, 2-deep register prefetch, masked max, project -> c[b][p]
// ---------------------------------------------------------------------------
__global__ __launch_bounds__(256, 2) void event_kernel(
    const float* __restrict__ table,
    const void* __restrict__ idxRaw,
    const void* __restrict__ maskRaw,
    const int* __restrict__ flags,
    const unsigned short* __restrict__ WtBf,
    const float* __restrict__ bt,
    const float* __restrict__ Wmm,
    const float* __restrict__ bmm,
    const float* __restrict__ bts,
    float* __restrict__ cOut)
{
    const int b = blockIdx.x;
    const int t = threadIdx.x;

    __shared__ __align__(16) unsigned short sA[2][64 * BK]; // 2 x 16KB, swizzled
    __shared__ int           sIdx[KEV];
    __shared__ unsigned char sMask[KEV];
    __shared__ float         sEv[HH];

    if (t < KEV) {
        const int i = b * KEV + t;
        int id;
        if (flags[0]) id = (int)((const long long*)idxRaw)[i];
        else          id = ((const int*)idxRaw)[i];
        sIdx[t] = id;
        const int mm = flags[1];
        bool mk;
        if      (mm == 0) mk = ((const unsigned char*)maskRaw)[i] != 0;
        else if (mm == 1) mk = ((const int*)maskRaw)[i] != 0;
        else              mk = ((const long long*)maskRaw)[i] != 0;
        sMask[t] = mk ? 1 : 0;
    }
    __syncthreads();

    // staging: 4 threads per event row, 32 floats (128B) each per step
    const int srow  = t >> 2;
    const int seoff = (t & 3) * 32;
    const float* rowp = table + (size_t)sIdx[srow] * EE_ + seoff;

    auto loadstep = [&](int s, float4 (&r)[8]) {
        const float4* p = reinterpret_cast<const float4*>(rowp + s * BK);
        #pragma unroll
        for (int j = 0; j < 8; ++j) r[j] = p[j];
    };
    // swizzle: e ^ ((row&7)<<3) ^ ((row&8)<<1)  -> 2-way on both rd & wr (free)
    auto writebuf = [&](int bufi, const float4 (&r)[8]) {
        unsigned short* base = &sA[bufi][srow * BK];
        const int swz = ((srow & 7) << 3) ^ ((srow & 8) << 1);
        #pragma unroll
        for (int j = 0; j < 4; ++j) {
            const float4 a = r[2 * j], c = r[2 * j + 1];
            ushort8_t o;
            o[0]=f2bf(a.x); o[1]=f2bf(a.y); o[2]=f2bf(a.z); o[3]=f2bf(a.w);
            o[4]=f2bf(c.x); o[5]=f2bf(c.y); o[6]=f2bf(c.z); o[7]=f2bf(c.w);
            *reinterpret_cast<ushort8_t*>(base + ((seoff + j * 8) ^ swz)) = o;
        }
    };

    const int w    = t >> 6;     // wave id: owns h-block [w*64, w*64+64)
    const int lane = t & 63;
    const int lm   = lane & 15;
    const int lg   = lane >> 4;

    f32x4 acc[4][4];
    #pragma unroll
    for (int mi = 0; mi < 4; ++mi)
        #pragma unroll
        for (int ni = 0; ni < 4; ++ni)
            acc[mi][ni] = (f32x4){0.f, 0.f, 0.f, 0.f};

    // B-fragment base: W_t bf16, h = w*64 + ni*16 + lm, e = s*BK + ks*32 + lg*8
    const unsigned short* wtB = WtBf + (size_t)(w * 64 + lm) * EE_ + lg * 8;

    auto mfma_step = [&](int cur, int s) {
        #pragma unroll
        for (int ks = 0; ks < 4; ++ks) {
            bf16x8 af[4];
            #pragma unroll
            for (int mi = 0; mi < 4; ++mi) {
                const int row = mi * 16 + lm;
                const int e   = ks * 32 + lg * 8;
                const int es  = e ^ ((row & 7) << 3) ^ ((row & 8) << 1);
                af[mi] = *reinterpret_cast<const bf16x8*>(&sA[cur][row * BK + es]);
            }
            #pragma unroll
            for (int ni = 0; ni < 4; ++ni) {
                const unsigned short* bp = wtB + (size_t)ni * 16 * EE_ + s * BK + ks * 32;
                bf16x8 bfr = *reinterpret_cast<const bf16x8*>(bp);
                #pragma unroll
                for (int mi = 0; mi < 4; ++mi)
                    acc[mi][ni] = __builtin_amdgcn_mfma_f32_16x16x32_bf16(
                        af[mi], bfr, acc[mi][ni], 0, 0, 0);
            }
        }
    };

    float4 rA[8], rB[8];
    loadstep(0, rA);
    writebuf(0, rA);
    loadstep(1, rA);                 // rA values consumed; safe to reuse
    __syncthreads();

    #pragma unroll
    for (int ss = 0; ss < NSTEP / 2; ++ss) {
        {   // even step s = 2*ss : next-step data in rA, prefetch into rB
            const int s = 2 * ss;
            if (s + 2 < NSTEP) loadstep(s + 2, rB);
            mfma_step(s & 1, s);
            writebuf((s + 1) & 1, rA);
            __syncthreads();
        }
        {   // odd step s = 2*ss+1 : next-step data in rB, prefetch into rA
            const int s = 2 * ss + 1;
            if (s + 2 < NSTEP) loadstep(s + 2, rA);
            mfma_step(s & 1, s);
            if (s + 1 < NSTEP) writebuf((s + 1) & 1, rB);
            __syncthreads();
        }
    }

    // Epilogue: masked max over 64 events per h column.
    // C/D layout: h = w*64 + ni*16 + (lane&15); event = mi*16 + (lane>>4)*4 + r
    #pragma unroll
    for (int ni = 0; ni < 4; ++ni) {
        float mx = -INFINITY;
        #pragma unroll
        for (int mi = 0; mi < 4; ++mi) {
            #pragma unroll
            for (int r = 0; r < 4; ++r) {
                const int ev = mi * 16 + lg * 4 + r;
                const float v = sMask[ev] ? acc[mi][ni][r] : -INFINITY;
                mx = fmaxf(mx, v);
            }
        }
        mx = fmaxf(mx, __shfl_xor(mx, 16));
        mx = fmaxf(mx, __shfl_xor(mx, 32));
        if (lg == 0) {
            const int h = w * 64 + ni * 16 + lm;
            sEv[h] = mx + bt[h];
        }
    }
    __syncthreads();

    // c[b][p] = sum_h ev_emb[h] * W_mm[p][h] + b_mm[p] + b_ts[p]   (wave 0)
    if (w == 0) {
        #pragma unroll 1
        for (int p = 0; p < PP; ++p) {
            const float* wr = Wmm + p * (HH + DD);
            float sum = sEv[lane]       * wr[lane]
                      + sEv[lane + 64]  * wr[lane + 64]
                      + sEv[lane + 128] * wr[lane + 128]
                      + sEv[lane + 192] * wr[lane + 192];
            #pragma unroll
            for (int off = 32; off >= 1; off >>= 1) sum += __shfl_xor(sum, off);
            if (lane == 0) cOut[b * PP + p] = sum + bmm[p] + bts[p];
        }
    }
}

// ---------------------------------------------------------------------------
// ts path, HIGH-OCCUPANCY rebuild: grid 2048 = (b, 256-col chunk); wave w of 4
// owns 32 d-rows; cross-wave d-reduction in LDS.  6 blocks/CU = 6 waves/SIMD
// (vs 2 before) to actually cover HBM latency.
//   out[b][p][n] = 0.5 * (sum_d Wc[p][d]*ts[b][d][n] + c[b][p])
// ---------------------------------------------------------------------------
__global__ __launch_bounds__(256) void ts_kernel(
    const float* __restrict__ ts,
    const float* __restrict__ Wc,
    const float* __restrict__ cIn,
    float* __restrict__ out)
{
    const int t   = threadIdx.x;
    const int b   = blockIdx.x >> 2;
    const int cid = blockIdx.x & 3;        // 256-column chunk
    const int w   = t >> 6;                // d-group: rows [32w, 32w+32)
    const int l   = t & 63;                // float4-column within chunk

    __shared__ f32x4 sRed[PP * 64];        // 12 KB, [p*64+l] -> conflict-free
    __shared__ float sC[PP];

    if (t < PP) sC[t] = cIn[b * PP + t];

    const float* tsb = ts + (size_t)b * DD * NN + (size_t)(w * 32) * NN
                          + cid * 256 + (l << 2);

    f32x4 tacc[PP];
    #pragma unroll
    for (int p = 0; p < PP; ++p) tacc[p] = (f32x4){0.f, 0.f, 0.f, 0.f};

    #pragma unroll 1
    for (int d0 = 0; d0 < 32; d0 += 8) {
        f32x4 v[8];
        #pragma unroll
        for (int j = 0; j < 8; ++j)
            v[j] = *reinterpret_cast<const f32x4*>(tsb + (size_t)(d0 + j) * NN);
        #pragma unroll
        for (int j = 0; j < 8; ++j) {
            const int d = w * 32 + d0 + j;
            #pragma unroll
            for (int p = 0; p < PP; ++p)
                tacc[p] += Wc[p * DD + d] * v[j];   // uniform -> s_load
        }
    }

    // sequential cross-wave reduction: w0 writes, w1/w2 add, w3 adds + stores
    if (w == 0) {
        #pragma unroll
        for (int p = 0; p < PP; ++p) sRed[p * 64 + l] = tacc[p];
    }
    __syncthreads();
    if (w == 1) {
        #pragma unroll
        for (int p = 0; p < PP; ++p) sRed[p * 64 + l] += tacc[p];
    }
    __syncthreads();
    if (w == 2) {
        #pragma unroll
        for (int p = 0; p < PP; ++p) sRed[p * 64 + l] += tacc[p];
    }
    __syncthreads();
    if (w == 3) {
        float* ob = out + (size_t)b * PP * NN + cid * 256 + (l << 2);
        #pragma unroll
        for (int p = 0; p < PP; ++p) {
            const float c = sC[p];
            const f32x4 r = (sRed[p * 64 + l] + tacc[p] + (f32x4){c, c, c, c}) * 0.5f;
            __builtin_nontemporal_store(r,
                reinterpret_cast<f32x4*>(ob + (size_t)p * NN));
        }
    }
}

// ---------------------------------------------------------------------------
extern "C" void kernel_launch(void* const* d_in, const int* in_sizes, int n_in,
                              void* d_out, int out_size, void* d_ws, size_t ws_size,
                              hipStream_t stream)
{
    const float* ts    = (const float*)d_in[0];
    const float* table = (const float*)d_in[1];
    const float* Wt    = (const float*)d_in[2];
    const float* bt    = (const float*)d_in[3];
    const float* Wmm   = (const float*)d_in[4];
    const float* bmm   = (const float*)d_in[5];
    const float* Wts   = (const float*)d_in[6];
    const float* bts   = (const float*)d_in[7];
    const void*  idx   = (const void*)d_in[8];
    const void*  msk   = (const void*)d_in[9];
    float* out = (float*)d_out;

    // ws layout: [0, 512KB) W_t bf16; [512KB, +8KB) Wc; cB[512][12]; flags
    unsigned short* WtBf = (unsigned short*)d_ws;
    float* Wc  = (float*)((char*)d_ws + (512u << 10));
    float* cB  = (float*)((char*)d_ws + (512u << 10) + 8192);
    int*   flg = (int*)((char*)d_ws + (512u << 10) + 8192 + B_ * PP * 4);

    prep_kernel<<<257, 256, 0, stream>>>(Wt, Wmm, Wts,
                                         (const unsigned int*)idx,
                                         (const unsigned int*)msk,
                                         WtBf, Wc, flg);
    event_kernel<<<B_, 256, 0, stream>>>(table, idx, msk, flg, WtBf, bt,
                                         Wmm, bmm, bts, cB);
    ts_kernel<<<4 * B_, 256, 0, stream>>>(ts, Wc, cB, out);
}

// Round 10
// 115.554 us; speedup vs baseline: 1.3748x; 1.3748x over previous
//
#include <hip/hip_runtime.h>
#include <hip/hip_bf16.h>
#include <math.h>

// Problem constants
#define B_   512
#define KEV  64
#define NN   1024
#define DD   128
#define EE_  1024
#define HH   256
#define PP   12
#define BKE  256                 // event K-step (elements of EE)
#define NSE  (EE_ / BKE)         // 4

typedef __bf16 bf16x8 __attribute__((ext_vector_type(8)));
typedef float  f32x4  __attribute__((ext_vector_type(4)));

static __device__ __forceinline__ unsigned short f2bf(float f) {
    unsigned int u = __builtin_bit_cast(unsigned int, f);
    u = (u + 0x7FFFu + ((u >> 16) & 1u)) >> 16;   // RNE
    return (unsigned short)u;
}

// ---------------------------------------------------------------------------
// prep (blocks 0..255): W_t f32 -> bf16.  block 256: detect dtypes + build Wc.
//   flags[0] = event_idx is int64 (1) or int32 (0)
//   flags[1] = event_mask repr: 0=uint8, 1=int32, 2=int64
// ---------------------------------------------------------------------------
__global__ __launch_bounds__(256) void prep_kernel(
    const float* __restrict__ Wt,
    const float* __restrict__ Wmm,
    const float* __restrict__ Wts,
    const unsigned int* __restrict__ idxW,
    const unsigned int* __restrict__ mskW,
    unsigned short* __restrict__ WtBf,
    float* __restrict__ Wc,
    int* __restrict__ flags)
{
    if (blockIdx.x < 256) {
        int i4 = (blockIdx.x * 256 + threadIdx.x) * 4;
        const float4 v = *reinterpret_cast<const float4*>(Wt + i4);
        ushort4 o = make_ushort4(f2bf(v.x), f2bf(v.y), f2bf(v.z), f2bf(v.w));
        *reinterpret_cast<ushort4*>(WtBf + i4) = o;
        return;
    }
    // block 256: detect + Wc
    __shared__ int any_nz;
    if (threadIdx.x == 0) any_nz = 0;
    __syncthreads();
    int local = 0;
    for (int k = threadIdx.x; k < (B_ * KEV) / 2; k += 256)
        local |= (idxW[2 * k + 1] != 0u);
    if (local) atomicOr(&any_nz, 1);
    for (int k = threadIdx.x; k < PP * DD; k += 256) {
        int p = k >> 7, d = k & 127;
        Wc[k] = Wmm[p * (HH + DD) + HH + d] + Wts[p * DD + d];
    }
    __syncthreads();
    if (threadIdx.x == 0) {
        flags[0] = any_nz ? 0 : 1;                 // 1 => idx is int64
        unsigned int w0 = mskW[0], w1 = mskW[1];
        flags[1] = (w0 == 0x01010101u) ? 0 : ((w1 == 0u) ? 2 : 1);
    }
}

// ---------------------------------------------------------------------------
// event path, WAVE-COALESCED gather: wave w owns rows [16w,16w+16); per row
// all 64 lanes load 1KB CONTIGUOUS (one m13-shaped instruction per row per
// step) -> DRAM sees whole 1KB islands instead of 64 scattered 64B lines per
// instruction.  BKE=256, 4 K-steps, LDS [64][256] bf16 double-buffered,
// XOR-swizzled.  MFMA layout + epilogue unchanged.
// ---------------------------------------------------------------------------
__global__ __launch_bounds__(256, 2) void event_kernel(
    const float* __restrict__ table,
    const void* __restrict__ idxRaw,
    const void* __restrict__ maskRaw,
    const int* __restrict__ flags,
    const unsigned short* __restrict__ WtBf,
    const float* __restrict__ bt,
    const float* __restrict__ Wmm,
    const float* __restrict__ bmm,
    const float* __restrict__ bts,
    float* __restrict__ cOut)
{
    const int b = blockIdx.x;
    const int t = threadIdx.x;
    const int w = t >> 6;        // wave id
    const int l = t & 63;        // lane

    __shared__ __align__(16) unsigned short sA[2][64 * BKE]; // 2 x 32KB
    __shared__ int           sIdx[KEV];
    __shared__ unsigned char sMask[KEV];
    __shared__ float         sEv[HH];

    if (t < KEV) {
        const int i = b * KEV + t;
        int id;
        if (flags[0]) id = (int)((const long long*)idxRaw)[i];
        else          id = ((const int*)idxRaw)[i];
        sIdx[t] = id;
        const int mm = flags[1];
        bool mk;
        if      (mm == 0) mk = ((const unsigned char*)maskRaw)[i] != 0;
        else if (mm == 1) mk = ((const int*)maskRaw)[i] != 0;
        else              mk = ((const long long*)maskRaw)[i] != 0;
        sMask[t] = mk ? 1 : 0;
    }
    __syncthreads();

    // per-wave row pointers: row w*16+i, lane offset l*4 floats (16B)
    const float* ptr[16];
    #pragma unroll
    for (int i = 0; i < 16; ++i)
        ptr[i] = table + (size_t)sIdx[w * 16 + i] * EE_ + (l << 2);

    auto loadstep = [&](int s, f32x4 (&r)[16]) {
        #pragma unroll
        for (int i = 0; i < 16; ++i)
            r[i] = *reinterpret_cast<const f32x4*>(ptr[i] + s * BKE);
    };
    // write: element group l*4 of row's step-slice at ((l*4)^sw) (8B store);
    // sw has only bits 3..5 -> 4-aligned XOR valid; 2 lanes/bank (free)
    auto writebuf = [&](int bufi, const f32x4 (&r)[16]) {
        #pragma unroll
        for (int i = 0; i < 16; ++i) {
            const int row = w * 16 + i;
            const int sw  = ((row & 7) << 3) ^ ((row & 8) << 1);
            ushort4 o = make_ushort4(f2bf(r[i][0]), f2bf(r[i][1]),
                                     f2bf(r[i][2]), f2bf(r[i][3]));
            *reinterpret_cast<ushort4*>(
                &sA[bufi][row * BKE + (((l << 2)) ^ sw)]) = o;
        }
    };

    const int lm = l & 15;
    const int lg = l >> 4;

    f32x4 acc[4][4];
    #pragma unroll
    for (int mi = 0; mi < 4; ++mi)
        #pragma unroll
        for (int ni = 0; ni < 4; ++ni)
            acc[mi][ni] = (f32x4){0.f, 0.f, 0.f, 0.f};

    // B-fragment base: W_t bf16, h = w*64 + ni*16 + lm, e = s*BKE + ks*32 + lg*8
    const unsigned short* wtB = WtBf + (size_t)(w * 64 + lm) * EE_ + lg * 8;

    auto mfma_step = [&](int cur, int s) {
        #pragma unroll
        for (int ks = 0; ks < 8; ++ks) {
            bf16x8 af[4];
            #pragma unroll
            for (int mi = 0; mi < 4; ++mi) {
                const int row = mi * 16 + lm;
                const int e   = ks * 32 + lg * 8;
                const int es  = e ^ (((row & 7) << 3) ^ ((row & 8) << 1));
                af[mi] = *reinterpret_cast<const bf16x8*>(&sA[cur][row * BKE + es]);
            }
            #pragma unroll
            for (int ni = 0; ni < 4; ++ni) {
                const unsigned short* bp = wtB + (size_t)ni * 16 * EE_ + s * BKE + ks * 32;
                bf16x8 bfr = *reinterpret_cast<const bf16x8*>(bp);
                #pragma unroll
                for (int mi = 0; mi < 4; ++mi)
                    acc[mi][ni] = __builtin_amdgcn_mfma_f32_16x16x32_bf16(
                        af[mi], bfr, acc[mi][ni], 0, 0, 0);
            }
        }
    };

    f32x4 rA[16];
    loadstep(0, rA);
    writebuf(0, rA);
    __syncthreads();

    #pragma unroll 1
    for (int s = 0; s < NSE; ++s) {
        if (s + 1 < NSE) loadstep(s + 1, rA);  // 64KB/block in flight...
        mfma_step(s & 1, s);                   // ...under 128 MFMAs/wave
        if (s + 1 < NSE) writebuf((s + 1) & 1, rA);
        __syncthreads();
    }

    // Epilogue: masked max over 64 events per h column.
    // C/D layout: h = w*64 + ni*16 + (lane&15); event = mi*16 + (lane>>4)*4 + r
    #pragma unroll
    for (int ni = 0; ni < 4; ++ni) {
        float mx = -INFINITY;
        #pragma unroll
        for (int mi = 0; mi < 4; ++mi) {
            #pragma unroll
            for (int r = 0; r < 4; ++r) {
                const int ev = mi * 16 + lg * 4 + r;
                const float v = sMask[ev] ? acc[mi][ni][r] : -INFINITY;
                mx = fmaxf(mx, v);
            }
        }
        mx = fmaxf(mx, __shfl_xor(mx, 16));
        mx = fmaxf(mx, __shfl_xor(mx, 32));
        if (lg == 0) {
            const int h = w * 64 + ni * 16 + lm;
            sEv[h] = mx + bt[h];
        }
    }
    __syncthreads();

    // c[b][p] = sum_h ev_emb[h] * W_mm[p][h] + b_mm[p] + b_ts[p]   (wave 0)
    if (w == 0) {
        #pragma unroll 1
        for (int p = 0; p < PP; ++p) {
            const float* wr = Wmm + p * (HH + DD);
            float sum = sEv[l]       * wr[l]
                      + sEv[l + 64]  * wr[l + 64]
                      + sEv[l + 128] * wr[l + 128]
                      + sEv[l + 192] * wr[l + 192];
            #pragma unroll
            for (int off = 32; off >= 1; off >>= 1) sum += __shfl_xor(sum, off);
            if (l == 0) cOut[b * PP + p] = sum + bmm[p] + bts[p];
        }
    }
}

// ---------------------------------------------------------------------------
// ts path (R4-proven): out[b][p][n] = 0.5*(sum_d Wc[p][d]*ts[b][d][n]+c[b][p])
// block = one batch; block-level access is a perfect sequential 512KB stream.
// ---------------------------------------------------------------------------
__global__ __launch_bounds__(256) void ts_kernel(
    const float* __restrict__ ts,
    const float* __restrict__ Wc,
    const float* __restrict__ cIn,
    float* __restrict__ out)
{
    const int b = blockIdx.x;
    const int t = threadIdx.x;

    __shared__ float sC[PP];
    __shared__ float sWc[PP * DD];
    if (t < PP) sC[t] = cIn[b * PP + t];
    for (int k = t; k < (PP * DD) / 4; k += 256)
        reinterpret_cast<float4*>(sWc)[k] = reinterpret_cast<const float4*>(Wc)[k];
    __syncthreads();

    const float* tsb = ts + (size_t)b * DD * NN + t * 4;

    f32x4 acc[PP];
    #pragma unroll
    for (int p = 0; p < PP; ++p) {
        const float c = sC[p];
        acc[p] = (f32x4){c, c, c, c};
    }

    #pragma unroll 4
    for (int d = 0; d < DD; ++d) {
        const f32x4 v = __builtin_nontemporal_load(
            reinterpret_cast<const f32x4*>(tsb + (size_t)d * NN));
        #pragma unroll
        for (int p = 0; p < PP; ++p) {
            acc[p] += sWc[p * DD + d] * v;     // uniform -> LDS broadcast
        }
    }

    float* ob = out + (size_t)b * PP * NN + t * 4;
    #pragma unroll
    for (int p = 0; p < PP; ++p) {
        const f32x4 r = acc[p] * 0.5f;
        __builtin_nontemporal_store(r, reinterpret_cast<f32x4*>(ob + (size_t)p * NN));
    }
}

// ---------------------------------------------------------------------------
extern "C" void kernel_launch(void* const* d_in, const int* in_sizes, int n_in,
                              void* d_out, int out_size, void* d_ws, size_t ws_size,
                              hipStream_t stream)
{
    const float* ts    = (const float*)d_in[0];
    const float* table = (const float*)d_in[1];
    const float* Wt    = (const float*)d_in[2];
    const float* bt    = (const float*)d_in[3];
    const float* Wmm   = (const float*)d_in[4];
    const float* bmm   = (const float*)d_in[5];
    const float* Wts   = (const float*)d_in[6];
    const float* bts   = (const float*)d_in[7];
    const void*  idx   = (const void*)d_in[8];
    const void*  msk   = (const void*)d_in[9];
    float* out = (float*)d_out;

    // ws layout: [0, 512KB) W_t bf16; [512KB, +8KB) Wc; cB[512][12]; flags
    unsigned short* WtBf = (unsigned short*)d_ws;
    float* Wc  = (float*)((char*)d_ws + (512u << 10));
    float* cB  = (float*)((char*)d_ws + (512u << 10) + 8192);
    int*   flg = (int*)((char*)d_ws + (512u << 10) + 8192 + B_ * PP * 4);

    prep_kernel<<<257, 256, 0, stream>>>(Wt, Wmm, Wts,
                                         (const unsigned int*)idx,
                                         (const unsigned int*)msk,
                                         WtBf, Wc, flg);
    event_kernel<<<B_, 256, 0, stream>>>(table, idx, msk, flg, WtBf, bt,
                                         Wmm, bmm, bts, cB);
    ts_kernel<<<B_, 256, 0, stream>>>(ts, Wc, cB, out);
}